// Round 2
// baseline (6060.393 us; speedup 1.0000x reference)
//
#include <hip/hip_runtime.h>
#include <hip/hip_bf16.h>

typedef unsigned short u16;
typedef unsigned int u32;

#define NG 100000
#define NV 200000
#define NE 500000
#define HD 128

__device__ __forceinline__ float bflo(u32 w) { return __uint_as_float(w << 16); }
__device__ __forceinline__ float bfhi(u32 w) { return __uint_as_float(w & 0xffff0000u); }
__device__ __forceinline__ u16 f2bf(float f) {
    __hip_bfloat16 h = __float2bfloat16(f);
    u16 u; __builtin_memcpy(&u, &h, 2); return u;
}

// ---- degree count: cnt[dst[e]] += 1 ----
__global__ __launch_bounds__(256) void count_kernel(const int* __restrict__ dst,
                                                    float* __restrict__ cnt, int E) {
    int e = blockIdx.x * 256 + threadIdx.x;
    if (e < E) unsafeAtomicAdd(&cnt[dst[e]], 1.0f);
}

// ---- rc = 1 / max(cnt, 1) ----
__global__ __launch_bounds__(256) void recip_kernel(float* __restrict__ rc, int N) {
    int i = blockIdx.x * 256 + threadIdx.x;
    if (i < N) rc[i] = 1.0f / fmaxf(rc[i], 1.0f);
}

// ---- scatter-add (f32 src): agg[dst[e]][:] += X[src[e]][:]  (32 thr/edge, float4) ----
__global__ __launch_bounds__(256) void scatter_f32_kernel(const float* __restrict__ X,
                                                          const int* __restrict__ src,
                                                          const int* __restrict__ dst,
                                                          float* __restrict__ agg, int E) {
    u32 t = blockIdx.x * 256 + threadIdx.x;
    u32 e = t >> 5, c = t & 31;
    if (e >= E) return;
    int s = src[e], d = dst[e];
    float4 v = *(const float4*)(X + (size_t)s * HD + c * 4);
    float* ap = agg + (size_t)d * HD + c * 4;
    unsafeAtomicAdd(ap + 0, v.x);
    unsafeAtomicAdd(ap + 1, v.y);
    unsafeAtomicAdd(ap + 2, v.z);
    unsafeAtomicAdd(ap + 3, v.w);
}

// ---- scatter-add (bf16 src): 16 thr/edge, 8 bf16 each ----
__global__ __launch_bounds__(256) void scatter_bf16_kernel(const u16* __restrict__ X,
                                                           const int* __restrict__ src,
                                                           const int* __restrict__ dst,
                                                           float* __restrict__ agg, int E) {
    u32 t = blockIdx.x * 256 + threadIdx.x;
    u32 e = t >> 4, c = t & 15;
    if (e >= E) return;
    int s = src[e], d = dst[e];
    uint4 u = *(const uint4*)(X + (size_t)s * HD + c * 8);
    float* ap = agg + (size_t)d * HD + c * 8;
    u32 w[4] = {u.x, u.y, u.z, u.w};
#pragma unroll
    for (int i = 0; i < 4; ++i) {
        unsafeAtomicAdd(ap + 2 * i,     bflo(w[i]));
        unsafeAtomicAdd(ap + 2 * i + 1, bfhi(w[i]));
    }
}

// ---- fused SAGE linear: out = act( (agg*rc) @ Wl^T + X @ Wr^T + b ) ----
// 64 rows x 128 cols per block, 256 threads, acc[4][8]/thread, f32 VALU FMA.
// agg == nullptr -> single-phase: out = act( X @ Wr^T + b )
// xbf16: X is bf16 (else f32). obf16: out is bf16 (else f32).
__global__ __launch_bounds__(256) void sage_gemm_kernel(
    const float* __restrict__ agg, const float* __restrict__ rc,
    const void* __restrict__ Xv, int xbf16,
    const float* __restrict__ Wl, const float* __restrict__ Wr,
    const float* __restrict__ bias,
    void* __restrict__ outv, int obf16, int N, int relu)
{
    __shared__ float As[64][132];
    __shared__ float Ws[32][132];
    const int tid = threadIdx.x;
    const int rowbase = blockIdx.x * 64;
    const int g = tid >> 4, li = tid & 15;
    const int jb = li * 8;

    float acc[4][8];
#pragma unroll
    for (int r = 0; r < 4; ++r)
#pragma unroll
        for (int c = 0; c < 8; ++c) acc[r][c] = 0.f;

    for (int phase = (agg != nullptr ? 0 : 1); phase < 2; ++phase) {
        __syncthreads();
        if (phase == 0 || !xbf16) {
            const float* srcp = (phase == 0) ? agg : (const float*)Xv;
#pragma unroll
            for (int cc = 0; cc < 8; ++cc) {
                int flat = cc * 1024 + tid * 4;
                int row = flat >> 7, col = flat & 127;
                int grow = rowbase + row;
                float4 v = make_float4(0.f, 0.f, 0.f, 0.f);
                if (grow < N) {
                    v = *(const float4*)(srcp + (size_t)grow * HD + col);
                    if (phase == 0) {
                        float s = rc[grow];
                        v.x *= s; v.y *= s; v.z *= s; v.w *= s;
                    }
                }
                *(float4*)&As[row][col] = v;
            }
        } else {
            const u16* X = (const u16*)Xv;
#pragma unroll
            for (int cc = 0; cc < 4; ++cc) {
                int flat = cc * 2048 + tid * 8;
                int row = flat >> 7, col = flat & 127;
                int grow = rowbase + row;
                float vf[8] = {0.f, 0.f, 0.f, 0.f, 0.f, 0.f, 0.f, 0.f};
                if (grow < N) {
                    uint4 u = *(const uint4*)(X + (size_t)grow * HD + col);
                    u32 w[4] = {u.x, u.y, u.z, u.w};
#pragma unroll
                    for (int i = 0; i < 4; ++i) { vf[2 * i] = bflo(w[i]); vf[2 * i + 1] = bfhi(w[i]); }
                }
                float4 v0 = {vf[0], vf[1], vf[2], vf[3]};
                float4 v1 = {vf[4], vf[5], vf[6], vf[7]};
                *(float4*)&As[row][col] = v0;
                *(float4*)&As[row][col + 4] = v1;
            }
        }
        const float* W = (phase == 0) ? Wl : Wr;
        for (int kc = 0; kc < 4; ++kc) {
            __syncthreads();
            {   // stage Ws[kk][j] = W[j][kc*32+kk] (transposed)
                int j = tid & 127;
                int kh = tid >> 7;
                const float* wp = W + (size_t)j * HD + kc * 32 + kh * 16;
                float4 a0 = *(const float4*)(wp);
                float4 a1 = *(const float4*)(wp + 4);
                float4 a2 = *(const float4*)(wp + 8);
                float4 a3 = *(const float4*)(wp + 12);
                float av[16] = {a0.x, a0.y, a0.z, a0.w, a1.x, a1.y, a1.z, a1.w,
                                a2.x, a2.y, a2.z, a2.w, a3.x, a3.y, a3.z, a3.w};
#pragma unroll
                for (int i = 0; i < 16; ++i) Ws[kh * 16 + i][j] = av[i];
            }
            __syncthreads();
#pragma unroll 8
            for (int kk = 0; kk < 32; ++kk) {
                int k = kc * 32 + kk;
                float av[4];
#pragma unroll
                for (int r = 0; r < 4; ++r) av[r] = As[4 * g + r][k];
                float4 w0 = *(const float4*)&Ws[kk][jb];
                float4 w1 = *(const float4*)&Ws[kk][jb + 4];
                float wv[8] = {w0.x, w0.y, w0.z, w0.w, w1.x, w1.y, w1.z, w1.w};
#pragma unroll
                for (int r = 0; r < 4; ++r)
#pragma unroll
                    for (int c = 0; c < 8; ++c)
                        acc[r][c] = fmaf(av[r], wv[c], acc[r][c]);
            }
        }
    }

    // epilogue: + bias, optional relu, write
    float bv[8];
#pragma unroll
    for (int c = 0; c < 8; ++c) bv[c] = bias[jb + c];
#pragma unroll
    for (int r = 0; r < 4; ++r) {
        int grow = rowbase + 4 * g + r;
        if (grow >= N) continue;
        float o[8];
#pragma unroll
        for (int c = 0; c < 8; ++c) {
            float v = acc[r][c] + bv[c];
            if (relu) v = fmaxf(v, 0.f);
            o[c] = v;
        }
        if (obf16) {
            uint4 pk;
            pk.x = (u32)f2bf(o[0]) | ((u32)f2bf(o[1]) << 16);
            pk.y = (u32)f2bf(o[2]) | ((u32)f2bf(o[3]) << 16);
            pk.z = (u32)f2bf(o[4]) | ((u32)f2bf(o[5]) << 16);
            pk.w = (u32)f2bf(o[6]) | ((u32)f2bf(o[7]) << 16);
            *(uint4*)((u16*)outv + (size_t)grow * HD + jb) = pk;
        } else {
            float* op = (float*)outv + (size_t)grow * HD + jb;
            *(float4*)(op)     = make_float4(o[0], o[1], o[2], o[3]);
            *(float4*)(op + 4) = make_float4(o[4], o[5], o[6], o[7]);
        }
    }
}

// ---- adversarial head stage 2: adv = hdn @ A2^T + b2  (128 -> 8), all f32 ----
__global__ __launch_bounds__(256) void head2_kernel(const float* __restrict__ hdn,
                                                    const float* __restrict__ A2,
                                                    const float* __restrict__ b2,
                                                    float* __restrict__ adv, int N)
{
    int tid = threadIdx.x;
    int r = blockIdx.x * 32 + (tid >> 3);
    int o = tid & 7;
    if (r >= N) return;
    const float* hp = hdn + (size_t)r * HD;
    const float* ap = A2 + (size_t)o * HD;
    float acc = 0.f;
#pragma unroll 8
    for (int k = 0; k < HD; k += 4) {
        float4 h = *(const float4*)(hp + k);
        float4 a = *(const float4*)(ap + k);
        acc = fmaf(h.x, a.x, acc);
        acc = fmaf(h.y, a.y, acc);
        acc = fmaf(h.z, a.z, acc);
        acc = fmaf(h.w, a.w, acc);
    }
    acc += b2[o];
    adv[(size_t)r * 8 + o] = acc;
}

extern "C" void kernel_launch(void* const* d_in, const int* in_sizes, int n_in,
                              void* d_out, int out_size, void* d_ws, size_t ws_size,
                              hipStream_t stream)
{
    const float* emb_gene = (const float*)d_in[0];
    const float* emb_var  = (const float*)d_in[1];
    const float* Wl1_gv = (const float*)d_in[2];
    const float* bl1_gv = (const float*)d_in[3];
    const float* Wr1_gv = (const float*)d_in[4];
    const float* Wl1_vg = (const float*)d_in[5];
    const float* bl1_vg = (const float*)d_in[6];
    const float* Wr1_vg = (const float*)d_in[7];
    const float* Wl2_gv = (const float*)d_in[8];
    const float* bl2_gv = (const float*)d_in[9];
    const float* Wr2_gv = (const float*)d_in[10];
    const float* Wl2_vg = (const float*)d_in[11];
    const float* bl2_vg = (const float*)d_in[12];
    const float* Wr2_vg = (const float*)d_in[13];
    const float* A1 = (const float*)d_in[14];
    const float* b1 = (const float*)d_in[15];
    const float* A2 = (const float*)d_in[16];
    const float* b2 = (const float*)d_in[17];
    const int* src_gv = (const int*)d_in[18];
    const int* dst_gv = (const int*)d_in[19];
    const int* src_vg = (const int*)d_in[20];
    const int* dst_vg = (const int*)d_in[21];

    // ws layout (bytes):
    //   agg_var  f32 [NV][128]   @ 0          (102,400,000)   (reused as hdn f32 [NG][128])
    //   agg_gene f32 [NG][128]   @ 102400000  ( 51,200,000)
    //   rc_var   f32 [NV]        @ 153600000  (    800,000)
    //   rc_gene  f32 [NG]        @ 154400000  (    400,000)
    //   z_var    bf16 [NV][128]  @ 154800000  ( 51,200,000)
    //   z_gene   bf16 [NG][128]  @ 206000000  ( 25,600,000)
    // total 231,600,000 bytes (round-1 run proves ws_size >= this)
    char* ws = (char*)d_ws;
    float* agg_var  = (float*)(ws);
    float* agg_gene = (float*)(ws + 102400000);
    float* rc_var   = (float*)(ws + 153600000);
    float* rc_gene  = (float*)(ws + 154400000);
    u16* z_var  = (u16*)(ws + 154800000);
    u16* z_gene = (u16*)(ws + 206000000);
    float* hdn = agg_var;  // reused after layer-2 GEMMs consumed agg_var

    float* out       = (float*)d_out;
    float* out_gene2 = out;                          // [NG][128]
    float* out_var2  = out + (size_t)NG * HD;        // [NV][128]
    float* out_adv   = out + (size_t)(NG + NV) * HD; // [NG][8]

    // zero aggs + degree counters
    hipMemsetAsync(ws, 0, 154800000, stream);

    // degrees (shared by both layers)
    count_kernel<<<(NE + 255) / 256, 256, 0, stream>>>(dst_gv, rc_var, NE);
    count_kernel<<<(NE + 255) / 256, 256, 0, stream>>>(dst_vg, rc_gene, NE);
    recip_kernel<<<(NV + 255) / 256, 256, 0, stream>>>(rc_var, NV);
    recip_kernel<<<(NG + 255) / 256, 256, 0, stream>>>(rc_gene, NG);

    // ---- layer 1 (f32 embeddings) ----
    scatter_f32_kernel<<<NE * 32 / 256, 256, 0, stream>>>(emb_gene, src_gv, dst_gv, agg_var, NE);
    scatter_f32_kernel<<<NE * 32 / 256, 256, 0, stream>>>(emb_var, src_vg, dst_vg, agg_gene, NE);
    sage_gemm_kernel<<<NV / 64, 256, 0, stream>>>(agg_var, rc_var, emb_var, 0,
                                                  Wl1_gv, Wr1_gv, bl1_gv, z_var, 1, NV, 1);
    sage_gemm_kernel<<<(NG + 63) / 64, 256, 0, stream>>>(agg_gene, rc_gene, emb_gene, 0,
                                                         Wl1_vg, Wr1_vg, bl1_vg, z_gene, 1, NG, 1);

    // ---- layer 2 (bf16 activations) ----
    hipMemsetAsync(ws, 0, 153600000, stream);  // re-zero aggs only (rc preserved)
    scatter_bf16_kernel<<<NE * 16 / 256, 256, 0, stream>>>(z_gene, src_gv, dst_gv, agg_var, NE);
    scatter_bf16_kernel<<<NE * 16 / 256, 256, 0, stream>>>(z_var, src_vg, dst_vg, agg_gene, NE);
    sage_gemm_kernel<<<NV / 64, 256, 0, stream>>>(agg_var, rc_var, z_var, 1,
                                                  Wl2_gv, Wr2_gv, bl2_gv, out_var2, 0, NV, 0);
    sage_gemm_kernel<<<(NG + 63) / 64, 256, 0, stream>>>(agg_gene, rc_gene, z_gene, 1,
                                                         Wl2_vg, Wr2_vg, bl2_vg, out_gene2, 0, NG, 0);

    // ---- adversarial head ----
    sage_gemm_kernel<<<(NG + 63) / 64, 256, 0, stream>>>(nullptr, nullptr, out_gene2, 0,
                                                         A1, A1, b1, hdn, 0, NG, 1);
    head2_kernel<<<(NG + 31) / 32, 256, 0, stream>>>(hdn, A2, b2, out_adv, NG);
}

// Round 3
// 986.579 us; speedup vs baseline: 6.1428x; 6.1428x over previous
//
#include <hip/hip_runtime.h>
#include <hip/hip_bf16.h>

typedef unsigned short u16;
typedef unsigned int u32;

#define NG 100000
#define NV 200000
#define NE 500000
#define HD 128

__device__ __forceinline__ float bflo(u32 w) { return __uint_as_float(w << 16); }
__device__ __forceinline__ float bfhi(u32 w) { return __uint_as_float(w & 0xffff0000u); }
__device__ __forceinline__ u16 f2bf(float f) {
    __hip_bfloat16 h = __float2bfloat16(f);
    u16 u; __builtin_memcpy(&u, &h, 2); return u;
}

// ---- histogram: deg[dst[e]] += 1 ----
__global__ __launch_bounds__(256) void hist_kernel(const int* __restrict__ dst,
                                                   int* __restrict__ deg, int E) {
    int e = blockIdx.x * 256 + threadIdx.x;
    if (e < E) atomicAdd(&deg[dst[e]], 1);
}

// ---- scan stage 1: per-block (2048 elems) exclusive scan + block sums ----
__global__ __launch_bounds__(256) void scan1_kernel(const int* __restrict__ deg,
                                                    int* __restrict__ excl,
                                                    int* __restrict__ bsum, int N) {
    __shared__ int lds[256];
    int tid = threadIdx.x;
    int base = blockIdx.x * 2048 + tid * 8;
    int v[8]; int s = 0;
#pragma unroll
    for (int i = 0; i < 8; ++i) { v[i] = (base + i < N) ? deg[base + i] : 0; s += v[i]; }
    lds[tid] = s;
    __syncthreads();
    for (int off = 1; off < 256; off <<= 1) {
        int x = (tid >= off) ? lds[tid - off] : 0;
        __syncthreads();
        lds[tid] += x;
        __syncthreads();
    }
    int run = lds[tid] - s;  // exclusive prefix of this thread within block
#pragma unroll
    for (int i = 0; i < 8; ++i) {
        if (base + i < N) excl[base + i] = run;
        run += v[i];
    }
    if (tid == 255) bsum[blockIdx.x] = lds[255];
}

// ---- scan stage 2: exclusive scan of block sums (nb <= 98, single thread) ----
__global__ void scan2_kernel(int* __restrict__ bsum, int nb) {
    if (threadIdx.x == 0 && blockIdx.x == 0) {
        int run = 0;
        for (int i = 0; i < nb; ++i) { int t = bsum[i]; bsum[i] = run; run += t; }
    }
}

// ---- scan stage 3: add block offsets; emit row_start (rs) and cursor copy ----
__global__ __launch_bounds__(256) void scan3_kernel(int* __restrict__ rs,
                                                    int* __restrict__ cur,
                                                    const int* __restrict__ bsum,
                                                    int N, int E) {
    int i = blockIdx.x * 256 + threadIdx.x;
    if (i < N) {
        int v = rs[i] + bsum[i >> 11];
        rs[i] = v;
        cur[i] = v;
    }
    if (i == 0) rs[N] = E;
}

// ---- edge scatter: esrc[cur[dst[e]]++] = src[e] (CSR adjacency build) ----
__global__ __launch_bounds__(256) void escatter_kernel(const int* __restrict__ src,
                                                       const int* __restrict__ dst,
                                                       int* __restrict__ cur,
                                                       int* __restrict__ esrc, int E) {
    int e = blockIdx.x * 256 + threadIdx.x;
    if (e < E) {
        int p = atomicAdd(&cur[dst[e]], 1);
        esrc[p] = src[e];
    }
}

// ---- gather-sum aggregate: aggb[row] = bf16( mean_{e in CSR[row]} X[esrc[e]] ) ----
// 16 threads per dst row, 8 feature cols each, f32 accumulation in registers.
template <int XBF16>
__global__ __launch_bounds__(256) void aggregate_kernel(const void* __restrict__ Xv,
                                                        const int* __restrict__ rs,
                                                        const int* __restrict__ esrc,
                                                        u16* __restrict__ aggb, int N) {
    u32 t = blockIdx.x * 256 + threadIdx.x;
    int row = t >> 4, c = t & 15;
    if (row >= N) return;
    int e0 = rs[row], e1 = rs[row + 1];
    float s[8] = {0.f, 0.f, 0.f, 0.f, 0.f, 0.f, 0.f, 0.f};
    if (XBF16) {
        const u16* X = (const u16*)Xv;
        for (int e = e0; e < e1; ++e) {
            const u16* p = X + (size_t)esrc[e] * HD + c * 8;
            uint4 u = *(const uint4*)p;
            u32 w[4] = {u.x, u.y, u.z, u.w};
#pragma unroll
            for (int i = 0; i < 4; ++i) { s[2 * i] += bflo(w[i]); s[2 * i + 1] += bfhi(w[i]); }
        }
    } else {
        const float* X = (const float*)Xv;
        for (int e = e0; e < e1; ++e) {
            const float* p = X + (size_t)esrc[e] * HD + c * 8;
            float4 a = *(const float4*)p;
            float4 b = *(const float4*)(p + 4);
            s[0] += a.x; s[1] += a.y; s[2] += a.z; s[3] += a.w;
            s[4] += b.x; s[5] += b.y; s[6] += b.z; s[7] += b.w;
        }
    }
    float rcv = 1.f / fmaxf((float)(e1 - e0), 1.f);
    uint4 pk;
    pk.x = (u32)f2bf(s[0] * rcv) | ((u32)f2bf(s[1] * rcv) << 16);
    pk.y = (u32)f2bf(s[2] * rcv) | ((u32)f2bf(s[3] * rcv) << 16);
    pk.z = (u32)f2bf(s[4] * rcv) | ((u32)f2bf(s[5] * rcv) << 16);
    pk.w = (u32)f2bf(s[6] * rcv) | ((u32)f2bf(s[7] * rcv) << 16);
    *(uint4*)(aggb + (size_t)row * HD + c * 8) = pk;
}

// ---- fused SAGE linear: out = act( Aagg @ Wl^T + X @ Wr^T + b ) ----
// Aagg: bf16 mean rows (nullable -> single-phase). X: bf16 or f32 per xbf16.
// 64 rows x 128 cols per block, 256 threads, acc[4][8]/thread, f32 VALU FMA.
__global__ __launch_bounds__(256) void sage_gemm_kernel(
    const u16* __restrict__ Aagg,
    const void* __restrict__ Xv, int xbf16,
    const float* __restrict__ Wl, const float* __restrict__ Wr,
    const float* __restrict__ bias,
    void* __restrict__ outv, int obf16, int N, int relu)
{
    __shared__ float As[64][132];
    __shared__ float Ws[32][132];
    const int tid = threadIdx.x;
    const int rowbase = blockIdx.x * 64;
    const int g = tid >> 4, li = tid & 15;
    const int jb = li * 8;

    float acc[4][8];
#pragma unroll
    for (int r = 0; r < 4; ++r)
#pragma unroll
        for (int c = 0; c < 8; ++c) acc[r][c] = 0.f;

    for (int phase = (Aagg != nullptr ? 0 : 1); phase < 2; ++phase) {
        __syncthreads();
        const u16* Bsrc = (phase == 0) ? Aagg : (xbf16 ? (const u16*)Xv : nullptr);
        if (Bsrc) {
#pragma unroll
            for (int cc = 0; cc < 4; ++cc) {
                int flat = cc * 2048 + tid * 8;
                int row = flat >> 7, col = flat & 127;
                int grow = rowbase + row;
                float vf[8] = {0.f, 0.f, 0.f, 0.f, 0.f, 0.f, 0.f, 0.f};
                if (grow < N) {
                    uint4 u = *(const uint4*)(Bsrc + (size_t)grow * HD + col);
                    u32 w[4] = {u.x, u.y, u.z, u.w};
#pragma unroll
                    for (int i = 0; i < 4; ++i) { vf[2 * i] = bflo(w[i]); vf[2 * i + 1] = bfhi(w[i]); }
                }
                float4 v0 = {vf[0], vf[1], vf[2], vf[3]};
                float4 v1 = {vf[4], vf[5], vf[6], vf[7]};
                *(float4*)&As[row][col] = v0;
                *(float4*)&As[row][col + 4] = v1;
            }
        } else {
            const float* srcp = (const float*)Xv;
#pragma unroll
            for (int cc = 0; cc < 8; ++cc) {
                int flat = cc * 1024 + tid * 4;
                int row = flat >> 7, col = flat & 127;
                int grow = rowbase + row;
                float4 v = make_float4(0.f, 0.f, 0.f, 0.f);
                if (grow < N) v = *(const float4*)(srcp + (size_t)grow * HD + col);
                *(float4*)&As[row][col] = v;
            }
        }
        const float* W = (phase == 0) ? Wl : Wr;
        for (int kc = 0; kc < 4; ++kc) {
            __syncthreads();
            {   // stage Ws[kk][j] = W[j][kc*32+kk] (transposed)
                int j = tid & 127;
                int kh = tid >> 7;
                const float* wp = W + (size_t)j * HD + kc * 32 + kh * 16;
                float4 a0 = *(const float4*)(wp);
                float4 a1 = *(const float4*)(wp + 4);
                float4 a2 = *(const float4*)(wp + 8);
                float4 a3 = *(const float4*)(wp + 12);
                float av[16] = {a0.x, a0.y, a0.z, a0.w, a1.x, a1.y, a1.z, a1.w,
                                a2.x, a2.y, a2.z, a2.w, a3.x, a3.y, a3.z, a3.w};
#pragma unroll
                for (int i = 0; i < 16; ++i) Ws[kh * 16 + i][j] = av[i];
            }
            __syncthreads();
#pragma unroll 8
            for (int kk = 0; kk < 32; ++kk) {
                int k = kc * 32 + kk;
                float av[4];
#pragma unroll
                for (int r = 0; r < 4; ++r) av[r] = As[4 * g + r][k];
                float4 w0 = *(const float4*)&Ws[kk][jb];
                float4 w1 = *(const float4*)&Ws[kk][jb + 4];
                float wv[8] = {w0.x, w0.y, w0.z, w0.w, w1.x, w1.y, w1.z, w1.w};
#pragma unroll
                for (int r = 0; r < 4; ++r)
#pragma unroll
                    for (int c = 0; c < 8; ++c)
                        acc[r][c] = fmaf(av[r], wv[c], acc[r][c]);
            }
        }
    }

    // epilogue: + bias, optional relu, write
    float bv[8];
#pragma unroll
    for (int c = 0; c < 8; ++c) bv[c] = bias[jb + c];
#pragma unroll
    for (int r = 0; r < 4; ++r) {
        int grow = rowbase + 4 * g + r;
        if (grow >= N) continue;
        float o[8];
#pragma unroll
        for (int c = 0; c < 8; ++c) {
            float v = acc[r][c] + bv[c];
            if (relu) v = fmaxf(v, 0.f);
            o[c] = v;
        }
        if (obf16) {
            uint4 pk;
            pk.x = (u32)f2bf(o[0]) | ((u32)f2bf(o[1]) << 16);
            pk.y = (u32)f2bf(o[2]) | ((u32)f2bf(o[3]) << 16);
            pk.z = (u32)f2bf(o[4]) | ((u32)f2bf(o[5]) << 16);
            pk.w = (u32)f2bf(o[6]) | ((u32)f2bf(o[7]) << 16);
            *(uint4*)((u16*)outv + (size_t)grow * HD + jb) = pk;
        } else {
            float* op = (float*)outv + (size_t)grow * HD + jb;
            *(float4*)(op)     = make_float4(o[0], o[1], o[2], o[3]);
            *(float4*)(op + 4) = make_float4(o[4], o[5], o[6], o[7]);
        }
    }
}

// ---- adversarial head stage 2: adv = hdn @ A2^T + b2  (128 -> 8), all f32 ----
__global__ __launch_bounds__(256) void head2_kernel(const float* __restrict__ hdn,
                                                    const float* __restrict__ A2,
                                                    const float* __restrict__ b2,
                                                    float* __restrict__ adv, int N)
{
    int tid = threadIdx.x;
    int r = blockIdx.x * 32 + (tid >> 3);
    int o = tid & 7;
    if (r >= N) return;
    const float* hp = hdn + (size_t)r * HD;
    const float* ap = A2 + (size_t)o * HD;
    float acc = 0.f;
#pragma unroll 8
    for (int k = 0; k < HD; k += 4) {
        float4 h = *(const float4*)(hp + k);
        float4 a = *(const float4*)(ap + k);
        acc = fmaf(h.x, a.x, acc);
        acc = fmaf(h.y, a.y, acc);
        acc = fmaf(h.z, a.z, acc);
        acc = fmaf(h.w, a.w, acc);
    }
    acc += b2[o];
    adv[(size_t)r * 8 + o] = acc;
}

extern "C" void kernel_launch(void* const* d_in, const int* in_sizes, int n_in,
                              void* d_out, int out_size, void* d_ws, size_t ws_size,
                              hipStream_t stream)
{
    const float* emb_gene = (const float*)d_in[0];
    const float* emb_var  = (const float*)d_in[1];
    const float* Wl1_gv = (const float*)d_in[2];
    const float* bl1_gv = (const float*)d_in[3];
    const float* Wr1_gv = (const float*)d_in[4];
    const float* Wl1_vg = (const float*)d_in[5];
    const float* bl1_vg = (const float*)d_in[6];
    const float* Wr1_vg = (const float*)d_in[7];
    const float* Wl2_gv = (const float*)d_in[8];
    const float* bl2_gv = (const float*)d_in[9];
    const float* Wr2_gv = (const float*)d_in[10];
    const float* Wl2_vg = (const float*)d_in[11];
    const float* bl2_vg = (const float*)d_in[12];
    const float* Wr2_vg = (const float*)d_in[13];
    const float* A1 = (const float*)d_in[14];
    const float* b1 = (const float*)d_in[15];
    const float* A2 = (const float*)d_in[16];
    const float* b2 = (const float*)d_in[17];
    const int* src_gv = (const int*)d_in[18];
    const int* dst_gv = (const int*)d_in[19];
    const int* src_vg = (const int*)d_in[20];
    const int* dst_vg = (const int*)d_in[21];

    // ws layout (bytes) — total 213.2 MB < 231.6 MB (proven available in round 1):
    //   agg_var  bf16 [NV][128]  @ 0            51,200,000
    //   agg_gene bf16 [NG][128]  @ 51,200,000   25,600,000
    //   z_var    bf16 [NV][128]  @ 76,800,000   51,200,000
    //   z_gene   bf16 [NG][128]  @ 128,000,000  25,600,000
    //   rs_var   i32 [NV+1]      @ 153,600,000     800,004
    //   rs_gene  i32 [NG+1]      @ 154,500,000     400,004
    //   esrc_gv  i32 [E]         @ 155,000,000   2,000,000
    //   esrc_vg  i32 [E]         @ 157,000,000   2,000,000
    //   deg_var  i32 [NV]        @ 159,000,000     800,000  (transient)
    //   deg_gene i32 [NG]        @ 159,800,000     400,000  (transient)
    //   cur_var  i32 [NV]        @ 160,200,000     800,000  (transient)
    //   cur_gene i32 [NG]        @ 161,000,000     400,000  (transient)
    //   bs_var   i32 [98]        @ 161,400,000         392
    //   bs_gene  i32 [49]        @ 161,500,000         196
    //   hdn      f32 [NG][128]   @ 162,000,000  51,200,000
    char* ws = (char*)d_ws;
    u16* agg_var  = (u16*)(ws);
    u16* agg_gene = (u16*)(ws + 51200000);
    u16* z_var    = (u16*)(ws + 76800000);
    u16* z_gene   = (u16*)(ws + 128000000);
    int* rs_var   = (int*)(ws + 153600000);
    int* rs_gene  = (int*)(ws + 154500000);
    int* esrc_gv  = (int*)(ws + 155000000);
    int* esrc_vg  = (int*)(ws + 157000000);
    int* deg_var  = (int*)(ws + 159000000);
    int* deg_gene = (int*)(ws + 159800000);
    int* cur_var  = (int*)(ws + 160200000);
    int* cur_gene = (int*)(ws + 161000000);
    int* bs_var   = (int*)(ws + 161400000);
    int* bs_gene  = (int*)(ws + 161500000);
    float* hdn    = (float*)(ws + 162000000);

    float* out       = (float*)d_out;
    float* out_gene2 = out;                          // [NG][128]
    float* out_var2  = out + (size_t)NG * HD;        // [NV][128]
    float* out_adv   = out + (size_t)(NG + NV) * HD; // [NG][8]

    const int NB_V = (NV + 2047) / 2048;  // 98
    const int NB_G = (NG + 2047) / 2048;  // 49
    const int EB = (NE + 255) / 256;      // 1954

    // ---- CSR build (both directions, reused by both layers) ----
    hipMemsetAsync(ws + 159000000, 0, 1200000, stream);  // deg_var + deg_gene
    hist_kernel<<<EB, 256, 0, stream>>>(dst_gv, deg_var, NE);
    hist_kernel<<<EB, 256, 0, stream>>>(dst_vg, deg_gene, NE);
    scan1_kernel<<<NB_V, 256, 0, stream>>>(deg_var, rs_var, bs_var, NV);
    scan1_kernel<<<NB_G, 256, 0, stream>>>(deg_gene, rs_gene, bs_gene, NG);
    scan2_kernel<<<1, 64, 0, stream>>>(bs_var, NB_V);
    scan2_kernel<<<1, 64, 0, stream>>>(bs_gene, NB_G);
    scan3_kernel<<<(NV + 255) / 256, 256, 0, stream>>>(rs_var, cur_var, bs_var, NV, NE);
    scan3_kernel<<<(NG + 255) / 256, 256, 0, stream>>>(rs_gene, cur_gene, bs_gene, NG, NE);
    escatter_kernel<<<EB, 256, 0, stream>>>(src_gv, dst_gv, cur_var, esrc_gv, NE);
    escatter_kernel<<<EB, 256, 0, stream>>>(src_vg, dst_vg, cur_gene, esrc_vg, NE);

    // ---- layer 1: aggregate f32 embeddings -> bf16 means; dual GEMM -> z (bf16) ----
    aggregate_kernel<0><<<NV * 16 / 256, 256, 0, stream>>>(emb_gene, rs_var, esrc_gv, agg_var, NV);
    aggregate_kernel<0><<<NG * 16 / 256, 256, 0, stream>>>(emb_var, rs_gene, esrc_vg, agg_gene, NG);
    sage_gemm_kernel<<<NV / 64, 256, 0, stream>>>(agg_var, emb_var, 0,
                                                  Wl1_gv, Wr1_gv, bl1_gv, z_var, 1, NV, 1);
    sage_gemm_kernel<<<(NG + 63) / 64, 256, 0, stream>>>(agg_gene, emb_gene, 0,
                                                         Wl1_vg, Wr1_vg, bl1_vg, z_gene, 1, NG, 1);

    // ---- layer 2: aggregate bf16 z -> bf16 means; dual GEMM -> d_out (f32) ----
    aggregate_kernel<1><<<NV * 16 / 256, 256, 0, stream>>>(z_gene, rs_var, esrc_gv, agg_var, NV);
    aggregate_kernel<1><<<NG * 16 / 256, 256, 0, stream>>>(z_var, rs_gene, esrc_vg, agg_gene, NG);
    sage_gemm_kernel<<<NV / 64, 256, 0, stream>>>(agg_var, z_var, 1,
                                                  Wl2_gv, Wr2_gv, bl2_gv, out_var2, 0, NV, 0);
    sage_gemm_kernel<<<(NG + 63) / 64, 256, 0, stream>>>(agg_gene, z_gene, 1,
                                                         Wl2_vg, Wr2_vg, bl2_vg, out_gene2, 0, NG, 0);

    // ---- adversarial head ----
    sage_gemm_kernel<<<(NG + 63) / 64, 256, 0, stream>>>(nullptr, out_gene2, 0,
                                                         A1, A1, b1, hdn, 0, NG, 1);
    head2_kernel<<<(NG + 31) / 32, 256, 0, stream>>>(hdn, A2, b2, out_adv, NG);
}

// Round 4
// 629.707 us; speedup vs baseline: 9.6241x; 1.5667x over previous
//
#include <hip/hip_runtime.h>
#include <hip/hip_bf16.h>

typedef unsigned short u16;
typedef unsigned int u32;
typedef __attribute__((ext_vector_type(8))) short bf16x8;
typedef __attribute__((ext_vector_type(4))) float f32x4;

#define NG 100000
#define NV 200000
#define NE 500000
#define HD 128

__device__ __forceinline__ float bflo(u32 w) { return __uint_as_float(w << 16); }
__device__ __forceinline__ float bfhi(u32 w) { return __uint_as_float(w & 0xffff0000u); }
__device__ __forceinline__ u16 f2bf(float f) {
    __hip_bfloat16 h = __float2bfloat16(f);
    u16 u; __builtin_memcpy(&u, &h, 2); return u;
}

// ---- histogram: deg[dst[e]] += 1 ----
__global__ __launch_bounds__(256) void hist_kernel(const int* __restrict__ dst,
                                                   int* __restrict__ deg, int E) {
    int e = blockIdx.x * 256 + threadIdx.x;
    if (e < E) atomicAdd(&deg[dst[e]], 1);
}

// ---- scan stage 1: per-block (2048 elems) exclusive scan + block sums ----
__global__ __launch_bounds__(256) void scan1_kernel(const int* __restrict__ deg,
                                                    int* __restrict__ excl,
                                                    int* __restrict__ bsum, int N) {
    __shared__ int lds[256];
    int tid = threadIdx.x;
    int base = blockIdx.x * 2048 + tid * 8;
    int v[8]; int s = 0;
#pragma unroll
    for (int i = 0; i < 8; ++i) { v[i] = (base + i < N) ? deg[base + i] : 0; s += v[i]; }
    lds[tid] = s;
    __syncthreads();
    for (int off = 1; off < 256; off <<= 1) {
        int x = (tid >= off) ? lds[tid - off] : 0;
        __syncthreads();
        lds[tid] += x;
        __syncthreads();
    }
    int run = lds[tid] - s;
#pragma unroll
    for (int i = 0; i < 8; ++i) {
        if (base + i < N) excl[base + i] = run;
        run += v[i];
    }
    if (tid == 255) bsum[blockIdx.x] = lds[255];
}

// ---- scan stage 2: exclusive scan of block sums ----
__global__ void scan2_kernel(int* __restrict__ bsum, int nb) {
    if (threadIdx.x == 0 && blockIdx.x == 0) {
        int run = 0;
        for (int i = 0; i < nb; ++i) { int t = bsum[i]; bsum[i] = run; run += t; }
    }
}

// ---- scan stage 3: add block offsets; emit row_start + cursor copy ----
__global__ __launch_bounds__(256) void scan3_kernel(int* __restrict__ rs,
                                                    int* __restrict__ cur,
                                                    const int* __restrict__ bsum,
                                                    int N, int E) {
    int i = blockIdx.x * 256 + threadIdx.x;
    if (i < N) {
        int v = rs[i] + bsum[i >> 11];
        rs[i] = v;
        cur[i] = v;
    }
    if (i == 0) rs[N] = E;
}

// ---- edge scatter: esrc[cur[dst[e]]++] = src[e] ----
__global__ __launch_bounds__(256) void escatter_kernel(const int* __restrict__ src,
                                                       const int* __restrict__ dst,
                                                       int* __restrict__ cur,
                                                       int* __restrict__ esrc, int E) {
    int e = blockIdx.x * 256 + threadIdx.x;
    if (e < E) {
        int p = atomicAdd(&cur[dst[e]], 1);
        esrc[p] = src[e];
    }
}

// ---- gather-sum aggregate: aggb[row] = bf16( mean_{e in CSR[row]} X[esrc[e]] ) ----
template <int XBF16>
__global__ __launch_bounds__(256) void aggregate_kernel(const void* __restrict__ Xv,
                                                        const int* __restrict__ rs,
                                                        const int* __restrict__ esrc,
                                                        u16* __restrict__ aggb, int N) {
    u32 t = blockIdx.x * 256 + threadIdx.x;
    int row = t >> 4, c = t & 15;
    if (row >= N) return;
    int e0 = rs[row], e1 = rs[row + 1];
    float s[8] = {0.f, 0.f, 0.f, 0.f, 0.f, 0.f, 0.f, 0.f};
    if (XBF16) {
        const u16* X = (const u16*)Xv;
        for (int e = e0; e < e1; ++e) {
            const u16* p = X + (size_t)esrc[e] * HD + c * 8;
            uint4 u = *(const uint4*)p;
            u32 w[4] = {u.x, u.y, u.z, u.w};
#pragma unroll
            for (int i = 0; i < 4; ++i) { s[2 * i] += bflo(w[i]); s[2 * i + 1] += bfhi(w[i]); }
        }
    } else {
        const float* X = (const float*)Xv;
        for (int e = e0; e < e1; ++e) {
            const float* p = X + (size_t)esrc[e] * HD + c * 8;
            float4 a = *(const float4*)p;
            float4 b = *(const float4*)(p + 4);
            s[0] += a.x; s[1] += a.y; s[2] += a.z; s[3] += a.w;
            s[4] += b.x; s[5] += b.y; s[6] += b.z; s[7] += b.w;
        }
    }
    float rcv = 1.f / fmaxf((float)(e1 - e0), 1.f);
    uint4 pk;
    pk.x = (u32)f2bf(s[0] * rcv) | ((u32)f2bf(s[1] * rcv) << 16);
    pk.y = (u32)f2bf(s[2] * rcv) | ((u32)f2bf(s[3] * rcv) << 16);
    pk.z = (u32)f2bf(s[4] * rcv) | ((u32)f2bf(s[5] * rcv) << 16);
    pk.w = (u32)f2bf(s[6] * rcv) | ((u32)f2bf(s[7] * rcv) << 16);
    *(uint4*)(aggb + (size_t)row * HD + c * 8) = pk;
}

// ---- MFMA fused SAGE linear: out = act( Agg @ Wl^T + X @ Wr^T + b ) ----
// 16x16x32 bf16 MFMA. Block = 256 thr = 4 waves; wave owns 64 rows (4 row-tiles).
// Weights (f32 in) staged once per block into fragment-linear LDS (bf16).
// Fragment map (m89-verified): A row=lane&15, k=8*(lane>>4)+j; B col=lane&15,
// same k; D col=lane&15, row=4*(lane>>4)+reg.
// HAS_AGG=0 -> single phase (X @ Wr^T only). XF32: X rows are f32.
template <int HAS_AGG, int XF32, int RELU>
__global__ __launch_bounds__(256, 2) void mfma_gemm_kernel(
    const u16* __restrict__ Agg,
    const void* __restrict__ Xv,
    const float* __restrict__ Wl, const float* __restrict__ Wr,
    const float* __restrict__ bias,
    float* __restrict__ outf, u16* __restrict__ outb, int N)
{
    constexpr int NPH = HAS_AGG ? 2 : 1;
    __shared__ u16 wlds[NPH][32][64][8];  // [phase][frag=kt*8+ct][lane][8] : 32KB/phase
    const int tid = threadIdx.x;

    // stage weights: f32 -> bf16, fragment-linear (conflict-free writes & reads)
#pragma unroll
    for (int p = 0; p < NPH; ++p) {
        const float* W = (NPH == 2 && p == 0) ? Wl : Wr;
#pragma unroll
        for (int it = 0; it < 8; ++it) {
            int slot = it * 256 + tid;       // 0..2047
            int f = slot >> 6, l = slot & 63;
            int kt = f >> 3, ct = f & 7;
            int row = ct * 16 + (l & 15);
            int kof = kt * 32 + (l >> 4) * 8;
            const float* wp = W + (size_t)row * HD + kof;
            float4 x = *(const float4*)wp;
            float4 y = *(const float4*)(wp + 4);
            uint4 pk;
            pk.x = (u32)f2bf(x.x) | ((u32)f2bf(x.y) << 16);
            pk.y = (u32)f2bf(x.z) | ((u32)f2bf(x.w) << 16);
            pk.z = (u32)f2bf(y.x) | ((u32)f2bf(y.y) << 16);
            pk.w = (u32)f2bf(y.z) | ((u32)f2bf(y.w) << 16);
            *(uint4*)&wlds[p][f][l][0] = pk;
        }
    }
    __syncthreads();

    const int lane = tid & 63;
    const int wid = tid >> 6;
    const int m0 = blockIdx.x * 256 + wid * 64;
    const int lr = lane & 15, lg = lane >> 4;

    f32x4 acc[4][8];
#pragma unroll
    for (int rt = 0; rt < 4; ++rt)
#pragma unroll
        for (int ct = 0; ct < 8; ++ct) acc[rt][ct] = (f32x4){0.f, 0.f, 0.f, 0.f};

#pragma unroll
    for (int ph = 0; ph < NPH; ++ph) {
        const bool isAgg = (NPH == 2 && ph == 0);
#pragma unroll
        for (int kt = 0; kt < 4; ++kt) {
            bf16x8 a[4];
            if (isAgg || !XF32) {
                const u16* A = isAgg ? Agg : (const u16*)Xv;
#pragma unroll
                for (int rt = 0; rt < 4; ++rt) {
                    int row = m0 + rt * 16 + lr; if (row > N - 1) row = N - 1;
                    a[rt] = *(const bf16x8*)(A + (size_t)row * HD + kt * 32 + lg * 8);
                }
            } else {
                const float* A = (const float*)Xv;
#pragma unroll
                for (int rt = 0; rt < 4; ++rt) {
                    int row = m0 + rt * 16 + lr; if (row > N - 1) row = N - 1;
                    const float* p = A + (size_t)row * HD + kt * 32 + lg * 8;
                    float4 x = *(const float4*)p;
                    float4 y = *(const float4*)(p + 4);
                    union { u16 s[8]; bf16x8 v; } u;
                    u.s[0] = f2bf(x.x); u.s[1] = f2bf(x.y); u.s[2] = f2bf(x.z); u.s[3] = f2bf(x.w);
                    u.s[4] = f2bf(y.x); u.s[5] = f2bf(y.y); u.s[6] = f2bf(y.z); u.s[7] = f2bf(y.w);
                    a[rt] = u.v;
                }
            }
#pragma unroll
            for (int ct = 0; ct < 8; ++ct) {
                bf16x8 wfrag = *(const bf16x8*)&wlds[ph][kt * 8 + ct][lane][0];
#pragma unroll
                for (int rt = 0; rt < 4; ++rt)
                    acc[rt][ct] = __builtin_amdgcn_mfma_f32_16x16x32_bf16(
                        a[rt], wfrag, acc[rt][ct], 0, 0, 0);
            }
        }
    }

    // epilogue: + bias, relu, store (D: col=lane&15, row=4*(lane>>4)+reg)
#pragma unroll
    for (int ct = 0; ct < 8; ++ct) {
        int col = ct * 16 + lr;
        float bcol = bias[col];
#pragma unroll
        for (int rt = 0; rt < 4; ++rt) {
            int rb = m0 + rt * 16 + lg * 4;
#pragma unroll
            for (int r = 0; r < 4; ++r) {
                int row = rb + r;
                if (row >= N) continue;
                float v = acc[rt][ct][r] + bcol;
                if (RELU) v = fmaxf(v, 0.f);
                if (outf) outf[(size_t)row * HD + col] = v;
                if (outb) outb[(size_t)row * HD + col] = f2bf(v);
            }
        }
    }
}

// ---- adversarial head stage 2: adv = hdn @ A2^T + b2  (128 -> 8), hdn bf16 ----
__global__ __launch_bounds__(256) void head2_kernel(const u16* __restrict__ hdn,
                                                    const float* __restrict__ A2,
                                                    const float* __restrict__ b2,
                                                    float* __restrict__ adv, int N)
{
    int tid = threadIdx.x;
    int r = blockIdx.x * 32 + (tid >> 3);
    int o = tid & 7;
    if (r >= N) return;
    const u16* hp = hdn + (size_t)r * HD;
    const float* ap = A2 + (size_t)o * HD;
    float acc = 0.f;
#pragma unroll 4
    for (int k = 0; k < HD; k += 8) {
        uint4 u = *(const uint4*)(hp + k);
        float4 a0 = *(const float4*)(ap + k);
        float4 a1 = *(const float4*)(ap + k + 4);
        u32 w[4] = {u.x, u.y, u.z, u.w};
        acc = fmaf(bflo(w[0]), a0.x, acc); acc = fmaf(bfhi(w[0]), a0.y, acc);
        acc = fmaf(bflo(w[1]), a0.z, acc); acc = fmaf(bfhi(w[1]), a0.w, acc);
        acc = fmaf(bflo(w[2]), a1.x, acc); acc = fmaf(bfhi(w[2]), a1.y, acc);
        acc = fmaf(bflo(w[3]), a1.z, acc); acc = fmaf(bfhi(w[3]), a1.w, acc);
    }
    adv[(size_t)r * 8 + o] = acc + b2[o];
}

extern "C" void kernel_launch(void* const* d_in, const int* in_sizes, int n_in,
                              void* d_out, int out_size, void* d_ws, size_t ws_size,
                              hipStream_t stream)
{
    const float* emb_gene = (const float*)d_in[0];
    const float* emb_var  = (const float*)d_in[1];
    const float* Wl1_gv = (const float*)d_in[2];
    const float* bl1_gv = (const float*)d_in[3];
    const float* Wr1_gv = (const float*)d_in[4];
    const float* Wl1_vg = (const float*)d_in[5];
    const float* bl1_vg = (const float*)d_in[6];
    const float* Wr1_vg = (const float*)d_in[7];
    const float* Wl2_gv = (const float*)d_in[8];
    const float* bl2_gv = (const float*)d_in[9];
    const float* Wr2_gv = (const float*)d_in[10];
    const float* Wl2_vg = (const float*)d_in[11];
    const float* bl2_vg = (const float*)d_in[12];
    const float* Wr2_vg = (const float*)d_in[13];
    const float* A1 = (const float*)d_in[14];
    const float* b1 = (const float*)d_in[15];
    const float* A2 = (const float*)d_in[16];
    const float* b2 = (const float*)d_in[17];
    const int* src_gv = (const int*)d_in[18];
    const int* dst_gv = (const int*)d_in[19];
    const int* src_vg = (const int*)d_in[20];
    const int* dst_vg = (const int*)d_in[21];

    // ws layout (bytes) — total ~213.1 MB < 231.6 MB proven:
    char* ws = (char*)d_ws;
    u16* agg_var  = (u16*)(ws);                 // bf16 [NV][128]  51.2 MB
    u16* agg_gene = (u16*)(ws + 51200000);      // bf16 [NG][128]  25.6 MB
    u16* z_var    = (u16*)(ws + 76800000);      // bf16 [NV][128]  51.2 MB
    u16* z_gene   = (u16*)(ws + 128000000);     // bf16 [NG][128]  25.6 MB
    u16* g2b      = (u16*)(ws + 153600000);     // bf16 [NG][128]  25.6 MB (gene2 for head)
    u16* hdn_b    = (u16*)(ws + 179200000);     // bf16 [NG][128]  25.6 MB
    int* rs_var   = (int*)(ws + 204800000);     // [NV+1]
    int* rs_gene  = (int*)(ws + 205700000);     // [NG+1]
    int* esrc_gv  = (int*)(ws + 206200000);     // [E]
    int* esrc_vg  = (int*)(ws + 208200000);     // [E]
    int* deg_var  = (int*)(ws + 210200000);     // [NV] transient
    int* deg_gene = (int*)(ws + 211000000);     // [NG] transient
    int* cur_var  = (int*)(ws + 211400000);     // [NV] transient
    int* cur_gene = (int*)(ws + 212200000);     // [NG] transient
    int* bs_var   = (int*)(ws + 213000000);     // [98]
    int* bs_gene  = (int*)(ws + 213100000);     // [49]

    float* out       = (float*)d_out;
    float* out_gene2 = out;                          // [NG][128]
    float* out_var2  = out + (size_t)NG * HD;        // [NV][128]
    float* out_adv   = out + (size_t)(NG + NV) * HD; // [NG][8]

    const int NB_V = (NV + 2047) / 2048;  // 98
    const int NB_G = (NG + 2047) / 2048;  // 49
    const int EB = (NE + 255) / 256;
    const int GB_V = (NV + 255) / 256;    // 782
    const int GB_G = (NG + 255) / 256;    // 391

    // ---- CSR build (shared by both layers) ----
    hipMemsetAsync(ws + 210200000, 0, 1200000, stream);  // deg_var + deg_gene
    hist_kernel<<<EB, 256, 0, stream>>>(dst_gv, deg_var, NE);
    hist_kernel<<<EB, 256, 0, stream>>>(dst_vg, deg_gene, NE);
    scan1_kernel<<<NB_V, 256, 0, stream>>>(deg_var, rs_var, bs_var, NV);
    scan1_kernel<<<NB_G, 256, 0, stream>>>(deg_gene, rs_gene, bs_gene, NG);
    scan2_kernel<<<1, 64, 0, stream>>>(bs_var, NB_V);
    scan2_kernel<<<1, 64, 0, stream>>>(bs_gene, NB_G);
    scan3_kernel<<<(NV + 255) / 256, 256, 0, stream>>>(rs_var, cur_var, bs_var, NV, NE);
    scan3_kernel<<<(NG + 255) / 256, 256, 0, stream>>>(rs_gene, cur_gene, bs_gene, NG, NE);
    escatter_kernel<<<EB, 256, 0, stream>>>(src_gv, dst_gv, cur_var, esrc_gv, NE);
    escatter_kernel<<<EB, 256, 0, stream>>>(src_vg, dst_vg, cur_gene, esrc_vg, NE);

    // ---- layer 1: f32 gather -> bf16 means; MFMA dual-GEMM -> z (bf16, relu) ----
    aggregate_kernel<0><<<NV * 16 / 256, 256, 0, stream>>>(emb_gene, rs_var, esrc_gv, agg_var, NV);
    aggregate_kernel<0><<<NG * 16 / 256, 256, 0, stream>>>(emb_var, rs_gene, esrc_vg, agg_gene, NG);
    mfma_gemm_kernel<1, 1, 1><<<GB_V, 256, 0, stream>>>(agg_var, emb_var,
        Wl1_gv, Wr1_gv, bl1_gv, nullptr, z_var, NV);
    mfma_gemm_kernel<1, 1, 1><<<GB_G, 256, 0, stream>>>(agg_gene, emb_gene,
        Wl1_vg, Wr1_vg, bl1_vg, nullptr, z_gene, NG);

    // ---- layer 2: bf16 gather -> bf16 means; MFMA dual-GEMM -> d_out (f32) ----
    aggregate_kernel<1><<<NV * 16 / 256, 256, 0, stream>>>(z_gene, rs_var, esrc_gv, agg_var, NV);
    aggregate_kernel<1><<<NG * 16 / 256, 256, 0, stream>>>(z_var, rs_gene, esrc_vg, agg_gene, NG);
    mfma_gemm_kernel<1, 0, 0><<<GB_V, 256, 0, stream>>>(agg_var, z_var,
        Wl2_gv, Wr2_gv, bl2_gv, out_var2, nullptr, NV);
    mfma_gemm_kernel<1, 0, 0><<<GB_G, 256, 0, stream>>>(agg_gene, z_gene,
        Wl2_vg, Wr2_vg, bl2_vg, out_gene2, g2b, NG);

    // ---- adversarial head ----
    mfma_gemm_kernel<0, 0, 1><<<GB_G, 256, 0, stream>>>(nullptr, g2b,
        A1, A1, b1, nullptr, hdn_b, NG);
    head2_kernel<<<(NG + 31) / 32, 256, 0, stream>>>(hdn_b, A2, b2, out_adv, NG);
}